// Round 1
// baseline (206.757 us; speedup 1.0000x reference)
//
#include <hip/hip_runtime.h>
#include <hip/hip_bf16.h>

#define B_   4
#define C_   256
#define CO_  256
#define H_   64
#define W_   64
#define HW_  4096
#define KK_  9

typedef __attribute__((ext_vector_type(8))) short short8;
typedef __attribute__((ext_vector_type(4))) float f32x4;

static __device__ __forceinline__ unsigned short f2bf(float f) {
    unsigned u = __builtin_bit_cast(unsigned, f);
    unsigned r = (u + 0x7fffu + ((u >> 16) & 1u)) >> 16;
    return (unsigned short)r;
}

// ---------------- K1: NCHW -> NHWC transpose (per batch C x HW -> HW x C) ------------
__global__ void k_transpose(const float* __restrict__ x, float* __restrict__ xT)
{
    __shared__ float tile[32][33];
    int bid = blockIdx.x;            // (b, hwT(128), cT(8))
    int cT  = bid & 7;
    int hwT = (bid >> 3) & 127;
    int b   = bid >> 10;
    int tid = threadIdx.x;
    int col = tid & 31;
    int row = tid >> 5;              // 0..7
    int c0 = cT * 32, hw0 = hwT * 32;
    const float* src = x + (size_t)b * C_ * HW_;
#pragma unroll
    for (int ps = 0; ps < 4; ++ps) {
        int c = c0 + row + ps * 8;
        tile[row + ps * 8][col] = src[(size_t)c * HW_ + hw0 + col];
    }
    __syncthreads();
    float* dst = xT + (size_t)b * HW_ * C_;
#pragma unroll
    for (int ps = 0; ps < 4; ++ps) {
        int hw = hw0 + row + ps * 8;
        dst[(size_t)hw * C_ + c0 + col] = tile[col][row + ps * 8];
    }
}

// ---------------- K2: offsets (dwconv + LN + relu + two dots -> ox, oy) --------------
__global__ void k_offsets(const float* __restrict__ xT,
                          const float* __restrict__ dwc_w,
                          const float* __restrict__ ln_w,
                          const float* __restrict__ ln_b,
                          const float* __restrict__ fcd_w,
                          const float* __restrict__ fca_w,
                          float* __restrict__ OX, float* __restrict__ OY)
{
    __shared__ float wsm[C_ * 9];
    __shared__ float red[16];
    int p = blockIdx.x;
    int b = p >> 12, rem = p & 4095, y = rem >> 6, x = rem & 63;
    int c = threadIdx.x;             // 256 threads = channels
    for (int i = c; i < C_ * 9; i += 256) wsm[i] = dwc_w[i];
    __syncthreads();

    float acc = 0.f;
#pragma unroll
    for (int j = 0; j < 9; ++j) {
        int yy = y + j / 3 - 1, xx = x + j % 3 - 1;
        if (yy >= 0 && yy < H_ && xx >= 0 && xx < W_)
            acc += wsm[c * 9 + j] * xT[((size_t)(((b << 6) + yy) << 6) + xx) * C_ + c];
    }

    int lane = c & 63, wid = c >> 6;
    float s1 = acc, s2 = acc * acc;
#pragma unroll
    for (int off = 32; off >= 1; off >>= 1) {
        s1 += __shfl_down(s1, off);
        s2 += __shfl_down(s2, off);
    }
    if (lane == 0) { red[wid] = s1; red[8 + wid] = s2; }
    __syncthreads();
    float tot1 = red[0] + red[1] + red[2] + red[3];
    float tot2 = red[8] + red[9] + red[10] + red[11];
    float mu  = tot1 * (1.f / 256.f);
    float var = tot2 * (1.f / 256.f) - mu * mu;
    float hn = (acc - mu) * rsqrtf(var + 1e-5f) * ln_w[c] + ln_b[c];
    hn = fmaxf(hn, 0.f);
    float d1 = hn * fcd_w[c], d2 = hn * fca_w[c];
#pragma unroll
    for (int off = 32; off >= 1; off >>= 1) {
        d1 += __shfl_down(d1, off);
        d2 += __shfl_down(d2, off);
    }
    __syncthreads();
    if (lane == 0) { red[wid] = d1; red[8 + wid] = d2; }
    __syncthreads();
    if (c == 0) {
        float r = red[0] + red[1] + red[2] + red[3];
        r = fmaxf(r, 0.f);
        float t = red[8] + red[9] + red[10] + red[11];
        float theta = t / (1.f + fabsf(t)) * 0.017453292519943295f;
        OX[p] = r * cosf(theta);
        OY[p] = r * sinf(theta);
    }
}

// ---------------- K3: pack dconv_w (Co,C,3,3) f32 -> Bt (N=256 x K=2304) bf16 --------
// K index kk = k*256 + c  (tap-major), Bt[o][kk]
__global__ void k_packB(const float* __restrict__ w, __hip_bfloat16* __restrict__ Bt)
{
    int idx = blockIdx.x * 256 + threadIdx.x;    // 589824 total
    int o = idx / 2304, kk = idx - o * 2304;
    int k = kk >> 8, c = kk & 255;
    unsigned short v = f2bf(w[(o * C_ + c) * 9 + k]);
    Bt[idx] = __builtin_bit_cast(__hip_bfloat16, v);
}

// ---------------- K4: implicit GEMM deformable conv ----------------------------------
// grid 256 blocks (one per (b,h) row of 64 positions), 512 threads = 8 waves.
// Per wave: 32 output channels (2 N-tiles) x 64 positions (4 M-tiles).
__launch_bounds__(512, 1)
__global__ void k_main(const float* __restrict__ xT,
                       const float* __restrict__ OX, const float* __restrict__ OY,
                       const __hip_bfloat16* __restrict__ Bt,
                       const float* __restrict__ bias,
                       float* __restrict__ out)
{
    __shared__ __align__(16) unsigned char smem[65536];  // A-tile (32KB swizzled) / epilogue (64KB)
    __shared__ float OXs[64], OYs[64];
    float* epi = (float*)smem;

    int tid = threadIdx.x;
    int p0 = blockIdx.x * 64;
    int b = p0 >> 12;
    int y = (p0 >> 6) & 63;
    if (tid < 64) { OXs[tid] = OX[p0 + tid]; OYs[tid] = OY[p0 + tid]; }

    int lane = tid & 63, wid = tid >> 6;
    int l15 = lane & 15, l4 = lane >> 4;

    f32x4 acc[4][2];
#pragma unroll
    for (int m = 0; m < 4; ++m)
#pragma unroll
        for (int n = 0; n < 2; ++n) {
            acc[m][n].x = 0.f; acc[m][n].y = 0.f; acc[m][n].z = 0.f; acc[m][n].w = 0.f;
        }

    int gpos = tid >> 3;              // 0..63 : position (w coordinate)
    int cblk = (tid & 7) << 5;        // 0..224 : 32-channel chunk
    const float* xb = xT + (size_t)b * HW_ * C_;

    __syncthreads();                  // OXs/OYs ready

    for (int k = 0; k < 9; ++k) {
        int ky = k / 3, kx = k - ky * 3;
        // ---- gather phase: build A_lds[64][256] bf16 (swizzled) for tap k ----
        float dyv = (k <= 4) ? OXs[gpos] : OYs[gpos];
        float dxv = (k <= 3) ? OXs[gpos] : OYs[gpos];
        float py = (float)(y - 1 + ky) + dyv;
        float px = (float)(gpos - 1 + kx) + dxv;
        float y0f = floorf(py), x0f = floorf(px);
        int y0 = (int)y0f, x0 = (int)x0f;
        int y1 = y0 + 1, x1 = x0 + 1;
        float wy1 = py - y0f, wy0 = 1.f - wy1;
        float wx1 = px - x0f, wx0 = 1.f - wx1;
        float vy0 = (y0 >= 0 && y0 < H_) ? 1.f : 0.f;
        float vy1 = (y1 >= 0 && y1 < H_) ? 1.f : 0.f;
        float vx0 = (x0 >= 0 && x0 < W_) ? 1.f : 0.f;
        float vx1 = (x1 >= 0 && x1 < W_) ? 1.f : 0.f;
        float w00 = wy0 * wx0 * vy0 * vx0, w01 = wy0 * wx1 * vy0 * vx1;
        float w10 = wy1 * wx0 * vy1 * vx0, w11 = wy1 * wx1 * vy1 * vx1;
        int y0c = min(max(y0, 0), H_ - 1), y1c = min(max(y1, 0), H_ - 1);
        int x0c = min(max(x0, 0), W_ - 1), x1c = min(max(x1, 0), W_ - 1);
        const float* p00 = xb + (size_t)((y0c << 6) + x0c) * C_ + cblk;
        const float* p01 = xb + (size_t)((y0c << 6) + x1c) * C_ + cblk;
        const float* p10 = xb + (size_t)((y1c << 6) + x0c) * C_ + cblk;
        const float* p11 = xb + (size_t)((y1c << 6) + x1c) * C_ + cblk;

        __syncthreads();              // previous MFMA phase done reading A_lds
        unsigned rowbase = (unsigned)gpos * 512u;
        unsigned swz = ((unsigned)gpos & 7u) << 4;
#pragma unroll
        for (int cc = 0; cc < 32; cc += 4) {
            f32x4 v00 = *(const f32x4*)(p00 + cc);
            f32x4 v01 = *(const f32x4*)(p01 + cc);
            f32x4 v10 = *(const f32x4*)(p10 + cc);
            f32x4 v11 = *(const f32x4*)(p11 + cc);
            f32x4 s = v00 * w00 + v01 * w01 + v10 * w10 + v11 * w11;
            ushort4 u;
            u.x = f2bf(s.x); u.y = f2bf(s.y); u.z = f2bf(s.z); u.w = f2bf(s.w);
            *(ushort4*)(smem + rowbase + ((((unsigned)(cblk + cc)) * 2u) ^ swz)) = u;
        }
        __syncthreads();              // A_lds ready

        // ---- MFMA phase ----
        const __hip_bfloat16* brow0 = Bt + (size_t)(wid * 32 + l15) * 2304 + (k << 8) + (l4 << 3);
#pragma unroll
        for (int ks = 0; ks < 8; ++ks) {
            int c0 = ks * 32;
            short8 a[4];
#pragma unroll
            for (int m = 0; m < 4; ++m) {
                int row = m * 16 + l15;
                unsigned off = (unsigned)row * 512u +
                               (((unsigned)(c0 * 2 + (l4 << 4))) ^ (((unsigned)row & 7u) << 4));
                a[m] = *(const short8*)(smem + off);
            }
            short8 bf0 = *(const short8*)(brow0 + c0);
            short8 bf1 = *(const short8*)(brow0 + 16 * 2304 + c0);
#pragma unroll
            for (int m = 0; m < 4; ++m) {
                acc[m][0] = __builtin_amdgcn_mfma_f32_16x16x32_bf16(a[m], bf0, acc[m][0], 0, 0, 0);
                acc[m][1] = __builtin_amdgcn_mfma_f32_16x16x32_bf16(a[m], bf1, acc[m][1], 0, 0, 0);
            }
        }
    }

    // ---- epilogue: LDS transpose then coalesced NCHW stores ----
    __syncthreads();
#pragma unroll
    for (int m = 0; m < 4; ++m)
#pragma unroll
        for (int n = 0; n < 2; ++n)
#pragma unroll
            for (int i = 0; i < 4; ++i) {
                int row = m * 16 + l4 * 4 + i;        // position (w)
                int col = wid * 32 + n * 16 + l15;    // output channel
                epi[row * 256 + col] = acc[m][n][i];
            }
    __syncthreads();
    int o  = tid >> 1;
    int wb = (tid & 1) << 5;
    float bv = bias[o];
    float* orow = out + (size_t)(((b * CO_ + o) * H_ + y) * W_);
#pragma unroll
    for (int w4 = 0; w4 < 32; w4 += 4) {
        f32x4 v;
        v.x = epi[(wb + w4 + 0) * 256 + o] + bv;
        v.y = epi[(wb + w4 + 1) * 256 + o] + bv;
        v.z = epi[(wb + w4 + 2) * 256 + o] + bv;
        v.w = epi[(wb + w4 + 3) * 256 + o] + bv;
        *(f32x4*)(orow + wb + w4) = v;
    }
}

extern "C" void kernel_launch(void* const* d_in, const int* in_sizes, int n_in,
                              void* d_out, int out_size, void* d_ws, size_t ws_size,
                              hipStream_t stream) {
    const float* x      = (const float*)d_in[0];
    const float* dwc_w  = (const float*)d_in[1];
    const float* ln_w   = (const float*)d_in[2];
    const float* ln_b   = (const float*)d_in[3];
    const float* fcd_w  = (const float*)d_in[4];
    const float* fca_w  = (const float*)d_in[5];
    const float* dconv_w= (const float*)d_in[6];
    const float* dconv_b= (const float*)d_in[7];
    float* out = (float*)d_out;

    unsigned char* ws = (unsigned char*)d_ws;
    float* xT = (float*)(ws);                                   // 16777216 B
    float* OX = (float*)(ws + 16777216);                        // 65536 B
    float* OY = (float*)(ws + 16842752);                        // 65536 B
    __hip_bfloat16* Bt = (__hip_bfloat16*)(ws + 16908288);      // 1179648 B

    k_transpose<<<B_ * 128 * 8, 256, 0, stream>>>(x, xT);
    k_packB<<<2304, 256, 0, stream>>>(dconv_w, Bt);
    k_offsets<<<B_ * HW_, 256, 0, stream>>>(xT, dwc_w, ln_w, ln_b, fcd_w, fca_w, OX, OY);
    k_main<<<256, 512, 0, stream>>>(xT, OX, OY, Bt, dconv_b, out);
}

// Round 2
// 164.095 us; speedup vs baseline: 1.2600x; 1.2600x over previous
//
#include <hip/hip_runtime.h>
#include <hip/hip_bf16.h>

#define B_   4
#define C_   256
#define CO_  256
#define H_   64
#define W_   64
#define HW_  4096
#define KK_  9

typedef __attribute__((ext_vector_type(8))) short short8;
typedef __attribute__((ext_vector_type(4))) float f32x4;

static __device__ __forceinline__ unsigned short f2bf(float f) {
    unsigned u = __builtin_bit_cast(unsigned, f);
    unsigned r = (u + 0x7fffu + ((u >> 16) & 1u)) >> 16;
    return (unsigned short)r;
}
static __device__ __forceinline__ float bf2f(unsigned short s) {
    unsigned u = ((unsigned)s) << 16;
    return __builtin_bit_cast(float, u);
}

// ---------------- K1: NCHW f32 -> NHWC bf16 transpose --------------------------------
__global__ void k_transpose(const float* __restrict__ x, unsigned short* __restrict__ xT)
{
    __shared__ float tile[32][33];
    int bid = blockIdx.x;            // (b, hwT(128), cT(8))
    int cT  = bid & 7;
    int hwT = (bid >> 3) & 127;
    int b   = bid >> 10;
    int tid = threadIdx.x;
    int col = tid & 31;
    int row = tid >> 5;              // 0..7
    int c0 = cT * 32, hw0 = hwT * 32;
    const float* src = x + (size_t)b * C_ * HW_;
#pragma unroll
    for (int ps = 0; ps < 4; ++ps) {
        int c = c0 + row + ps * 8;
        tile[row + ps * 8][col] = src[(size_t)c * HW_ + hw0 + col];
    }
    __syncthreads();
    unsigned short* dst = xT + (size_t)b * HW_ * C_;
#pragma unroll
    for (int ps = 0; ps < 4; ++ps) {
        int hw = hw0 + row + ps * 8;
        dst[(size_t)hw * C_ + c0 + col] = f2bf(tile[col][row + ps * 8]);
    }
}

// ---------------- K2: offsets (dwconv + LN + relu + two dots -> ox, oy) --------------
__global__ void k_offsets(const unsigned short* __restrict__ xT,
                          const float* __restrict__ dwc_w,
                          const float* __restrict__ ln_w,
                          const float* __restrict__ ln_b,
                          const float* __restrict__ fcd_w,
                          const float* __restrict__ fca_w,
                          float* __restrict__ OX, float* __restrict__ OY)
{
    __shared__ float wsm[C_ * 9];
    __shared__ float red[16];
    int bi = blockIdx.x;
    int p = ((bi & 7) << 11) + (bi >> 3);    // XCD swizzle: 2048 consecutive positions per XCD
    int b = p >> 12, rem = p & 4095, y = rem >> 6, x = rem & 63;
    int c = threadIdx.x;             // 256 threads = channels
    for (int i = c; i < C_ * 9; i += 256) wsm[i] = dwc_w[i];
    __syncthreads();

    float acc = 0.f;
#pragma unroll
    for (int j = 0; j < 9; ++j) {
        int yy = y + j / 3 - 1, xx = x + j % 3 - 1;
        if (yy >= 0 && yy < H_ && xx >= 0 && xx < W_)
            acc += wsm[c * 9 + j] * bf2f(xT[((size_t)(((b << 6) + yy) << 6) + xx) * C_ + c]);
    }

    int lane = c & 63, wid = c >> 6;
    float s1 = acc, s2 = acc * acc;
#pragma unroll
    for (int off = 32; off >= 1; off >>= 1) {
        s1 += __shfl_down(s1, off);
        s2 += __shfl_down(s2, off);
    }
    if (lane == 0) { red[wid] = s1; red[8 + wid] = s2; }
    __syncthreads();
    float tot1 = red[0] + red[1] + red[2] + red[3];
    float tot2 = red[8] + red[9] + red[10] + red[11];
    float mu  = tot1 * (1.f / 256.f);
    float var = tot2 * (1.f / 256.f) - mu * mu;
    float hn = (acc - mu) * rsqrtf(var + 1e-5f) * ln_w[c] + ln_b[c];
    hn = fmaxf(hn, 0.f);
    float d1 = hn * fcd_w[c], d2 = hn * fca_w[c];
#pragma unroll
    for (int off = 32; off >= 1; off >>= 1) {
        d1 += __shfl_down(d1, off);
        d2 += __shfl_down(d2, off);
    }
    __syncthreads();
    if (lane == 0) { red[wid] = d1; red[8 + wid] = d2; }
    __syncthreads();
    if (c == 0) {
        float r = red[0] + red[1] + red[2] + red[3];
        r = fmaxf(r, 0.f);
        float t = red[8] + red[9] + red[10] + red[11];
        float theta = t / (1.f + fabsf(t)) * 0.017453292519943295f;
        OX[p] = r * cosf(theta);
        OY[p] = r * sinf(theta);
    }
}

// ---------------- K3: pack dconv_w (Co,C,3,3) f32 -> Bt (N=256 x K=2304) bf16 --------
__global__ void k_packB(const float* __restrict__ w, unsigned short* __restrict__ Bt)
{
    int idx = blockIdx.x * 256 + threadIdx.x;    // 589824 total
    int o = idx / 2304, kk = idx - o * 2304;
    int k = kk >> 8, c = kk & 255;
    Bt[idx] = f2bf(w[(o * C_ + c) * 9 + k]);
}

// ---------------- K4: implicit GEMM deformable conv ----------------------------------
// 512 blocks (XCD-swizzled, 32 positions each = half a (b,y) row), 256 threads = 4 waves.
// Wave: 64 output channels (4 N-frags) x 32 positions (2 M-frags).
__launch_bounds__(256, 4)
__global__ void k_main(const unsigned short* __restrict__ xT,
                       const float* __restrict__ OX, const float* __restrict__ OY,
                       const unsigned short* __restrict__ Bt,
                       const float* __restrict__ bias,
                       float* __restrict__ out)
{
    __shared__ __align__(16) unsigned char smem[32768];  // A-tile 16KB / epilogue 32KB
    __shared__ float OXs[32], OYs[32];
    float* epi = (float*)smem;

    int tid = threadIdx.x;
    int bi = blockIdx.x;
    int swz = ((bi & 7) << 6) + (bi >> 3);   // XCD g owns 64 consecutive 32-pos chunks
    int p0 = swz << 5;
    int b = p0 >> 12;
    int y = (p0 >> 6) & 63;
    int xh = p0 & 63;                        // 0 or 32
    if (tid < 32) { OXs[tid] = OX[p0 + tid]; OYs[tid] = OY[p0 + tid]; }

    int lane = tid & 63, wid = tid >> 6;
    int l15 = lane & 15, l4 = lane >> 4;

    f32x4 acc[2][4];
#pragma unroll
    for (int m = 0; m < 2; ++m)
#pragma unroll
        for (int n = 0; n < 4; ++n) {
            acc[m][n].x = 0.f; acc[m][n].y = 0.f; acc[m][n].z = 0.f; acc[m][n].w = 0.f;
        }

    int gpos = tid >> 3;              // 0..31 : position within block
    int cblk = (tid & 7) << 5;        // 32-channel chunk
    const unsigned short* xb = xT + (size_t)b * HW_ * C_;

    __syncthreads();                  // OXs/OYs ready

    for (int k = 0; k < 9; ++k) {
        int ky = k / 3, kx = k - ky * 3;
        float dyv = (k <= 4) ? OXs[gpos] : OYs[gpos];
        float dxv = (k <= 3) ? OXs[gpos] : OYs[gpos];
        float py = (float)(y - 1 + ky) + dyv;
        float px = (float)(xh + gpos - 1 + kx) + dxv;
        float y0f = floorf(py), x0f = floorf(px);
        int y0 = (int)y0f, x0 = (int)x0f;
        int y1 = y0 + 1, x1 = x0 + 1;
        float wy1 = py - y0f, wy0 = 1.f - wy1;
        float wx1 = px - x0f, wx0 = 1.f - wx1;
        float vy0 = (y0 >= 0 && y0 < H_) ? 1.f : 0.f;
        float vy1 = (y1 >= 0 && y1 < H_) ? 1.f : 0.f;
        float vx0 = (x0 >= 0 && x0 < W_) ? 1.f : 0.f;
        float vx1 = (x1 >= 0 && x1 < W_) ? 1.f : 0.f;
        float w00 = wy0 * wx0 * vy0 * vx0, w01 = wy0 * wx1 * vy0 * vx1;
        float w10 = wy1 * wx0 * vy1 * vx0, w11 = wy1 * wx1 * vy1 * vx1;
        int y0c = min(max(y0, 0), H_ - 1), y1c = min(max(y1, 0), H_ - 1);
        int x0c = min(max(x0, 0), W_ - 1), x1c = min(max(x1, 0), W_ - 1);
        const unsigned short* p00 = xb + (size_t)((y0c << 6) + x0c) * C_ + cblk;
        const unsigned short* p01 = xb + (size_t)((y0c << 6) + x1c) * C_ + cblk;
        const unsigned short* p10 = xb + (size_t)((y1c << 6) + x0c) * C_ + cblk;
        const unsigned short* p11 = xb + (size_t)((y1c << 6) + x1c) * C_ + cblk;

        __syncthreads();              // previous MFMA phase done reading A_lds
        unsigned rowbase = (unsigned)gpos * 512u;
        unsigned swzr = ((unsigned)gpos & 7u) << 4;
#pragma unroll
        for (int cc = 0; cc < 32; cc += 8) {
            short8 r00 = *(const short8*)(p00 + cc);
            short8 r01 = *(const short8*)(p01 + cc);
            short8 r10 = *(const short8*)(p10 + cc);
            short8 r11 = *(const short8*)(p11 + cc);
            short8 res;
#pragma unroll
            for (int j = 0; j < 8; ++j) {
                float a = bf2f((unsigned short)r00[j]) * w00
                        + bf2f((unsigned short)r01[j]) * w01
                        + bf2f((unsigned short)r10[j]) * w10
                        + bf2f((unsigned short)r11[j]) * w11;
                res[j] = (short)f2bf(a);
            }
            *(short8*)(smem + rowbase + ((((unsigned)(cblk + cc)) * 2u) ^ swzr)) = res;
        }
        __syncthreads();              // A_lds ready

        // ---- MFMA phase ----
        const unsigned short* brow0 = Bt + (size_t)(wid * 64 + l15) * 2304 + (k << 8) + (l4 << 3);
#pragma unroll
        for (int ks = 0; ks < 8; ++ks) {
            int c0 = ks * 32;
            short8 a[2];
#pragma unroll
            for (int m = 0; m < 2; ++m) {
                int row = m * 16 + l15;
                unsigned off = (unsigned)row * 512u +
                               (((unsigned)(c0 * 2 + (l4 << 4))) ^ (((unsigned)row & 7u) << 4));
                a[m] = *(const short8*)(smem + off);
            }
#pragma unroll
            for (int n = 0; n < 4; ++n) {
                short8 bf = *(const short8*)(brow0 + (size_t)n * 16 * 2304 + c0);
#pragma unroll
                for (int m = 0; m < 2; ++m)
                    acc[m][n] = __builtin_amdgcn_mfma_f32_16x16x32_bf16(a[m], bf, acc[m][n], 0, 0, 0);
            }
        }
    }

    // ---- epilogue: LDS transpose then NCHW stores ----
    __syncthreads();
#pragma unroll
    for (int m = 0; m < 2; ++m)
#pragma unroll
        for (int n = 0; n < 4; ++n)
#pragma unroll
            for (int i = 0; i < 4; ++i) {
                int row = m * 16 + l4 * 4 + i;        // position
                int col = wid * 64 + n * 16 + l15;    // output channel
                epi[row * 256 + col] = acc[m][n][i];
            }
    __syncthreads();
    int o = tid;
    float bv = bias[o];
    float* orow = out + (size_t)(((b * CO_ + o) * H_ + y) * W_) + xh;
#pragma unroll
    for (int w4 = 0; w4 < 32; w4 += 4) {
        f32x4 v;
        v.x = epi[(w4 + 0) * 256 + o] + bv;
        v.y = epi[(w4 + 1) * 256 + o] + bv;
        v.z = epi[(w4 + 2) * 256 + o] + bv;
        v.w = epi[(w4 + 3) * 256 + o] + bv;
        *(f32x4*)(orow + w4) = v;
    }
}

extern "C" void kernel_launch(void* const* d_in, const int* in_sizes, int n_in,
                              void* d_out, int out_size, void* d_ws, size_t ws_size,
                              hipStream_t stream) {
    const float* x      = (const float*)d_in[0];
    const float* dwc_w  = (const float*)d_in[1];
    const float* ln_w   = (const float*)d_in[2];
    const float* ln_b   = (const float*)d_in[3];
    const float* fcd_w  = (const float*)d_in[4];
    const float* fca_w  = (const float*)d_in[5];
    const float* dconv_w= (const float*)d_in[6];
    const float* dconv_b= (const float*)d_in[7];
    float* out = (float*)d_out;

    unsigned char* ws = (unsigned char*)d_ws;
    unsigned short* xT = (unsigned short*)(ws);                 // 8388608 B (bf16 NHWC)
    float* OX = (float*)(ws + 8388608);                         // 65536 B
    float* OY = (float*)(ws + 8454144);                         // 65536 B
    unsigned short* Bt = (unsigned short*)(ws + 8519680);       // 1179648 B

    k_transpose<<<B_ * 128 * 8, 256, 0, stream>>>(x, xT);
    k_packB<<<2304, 256, 0, stream>>>(dconv_w, Bt);
    k_offsets<<<B_ * HW_, 256, 0, stream>>>(xT, dwc_w, ln_w, ln_b, fcd_w, fca_w, OX, OY);
    k_main<<<512, 256, 0, stream>>>(xT, OX, OY, Bt, dconv_b, out);
}

// Round 3
// 128.333 us; speedup vs baseline: 1.6111x; 1.2787x over previous
//
#include <hip/hip_runtime.h>
#include <hip/hip_bf16.h>

#define B_   4
#define C_   256
#define CO_  256
#define H_   64
#define W_   64
#define HW_  4096

typedef __attribute__((ext_vector_type(8))) short short8;
typedef __attribute__((ext_vector_type(4))) float f32x4;

static __device__ __forceinline__ unsigned short f2bf(float f) {
    unsigned u = __builtin_bit_cast(unsigned, f);
    unsigned r = (u + 0x7fffu + ((u >> 16) & 1u)) >> 16;
    return (unsigned short)r;
}
static __device__ __forceinline__ float bf2f(unsigned short s) {
    unsigned u = ((unsigned)s) << 16;
    return __builtin_bit_cast(float, u);
}

// ---------------- K1: NCHW f32 -> NHWC bf16 transpose (32hw x 128c tiles) ------------
__global__ void k_transpose(const float* __restrict__ x, unsigned short* __restrict__ xT)
{
    __shared__ float t[32][136];     // [hw][c], pad to 136 for aligned float4 reads
    int bid = blockIdx.x;            // 1024 = b(4) * hwT(128) * cT(2)
    int b   = bid >> 8;
    int rem = bid & 255;
    int hwT = rem >> 1, cT = rem & 1;
    int hw0 = hwT * 32, c0 = cT * 128;
    int tid = threadIdx.x;
    const float* src = x + (size_t)b * C_ * HW_;
    {
        int hwi = tid & 31, cr = tid >> 5;   // cr 0..7
#pragma unroll
        for (int ps = 0; ps < 16; ++ps) {
            int c = cr + ps * 8;
            t[hwi][c] = src[(size_t)(c0 + c) * HW_ + hw0 + hwi];
        }
    }
    __syncthreads();
    {
        int c4 = (tid & 31) * 4, hwr = tid >> 5;
        unsigned short* dst = xT + (size_t)(((b << 12) + hw0) * 256) + c0 + c4;
#pragma unroll
        for (int ps = 0; ps < 4; ++ps) {
            int hw = hwr + ps * 8;
            f32x4 v = *(const f32x4*)&t[hw][c4];
            ushort4 u;
            u.x = f2bf(v.x); u.y = f2bf(v.y); u.z = f2bf(v.z); u.w = f2bf(v.w);
            *(ushort4*)(dst + (size_t)hw * 256) = u;
        }
    }
}

// ---------------- K2: offsets — 8 positions per block, LDS window ---------------------
__global__ void k_offsets(const unsigned short* __restrict__ xT,
                          const float* __restrict__ dwc_w,
                          const float* __restrict__ ln_w,
                          const float* __restrict__ ln_b,
                          const float* __restrict__ fcd_w,
                          const float* __restrict__ fca_w,
                          float* __restrict__ OX, float* __restrict__ OY)
{
    __shared__ unsigned short win[30][256];   // [r*10+xc][ch]
    __shared__ float red[2][4][16];           // [parity][s1,s2,d1,d2][wave]
    int bi = blockIdx.x;
    int oct = ((bi & 7) << 8) | (bi >> 3);    // XCD swizzle, matches k_main ownership
    int b = oct >> 9, rem = oct & 511, y = rem >> 3, xo = (rem & 7) << 3;
    int c = threadIdx.x;

    for (int i = 0; i < 30; ++i) {
        int r = i / 10, xc = i - r * 10;
        int gy = y - 1 + r, gx = xo - 1 + xc;
        unsigned short v = 0;
        if (gy >= 0 && gy < H_ && gx >= 0 && gx < W_)
            v = xT[((size_t)(((b << 6) + gy) << 6) + gx) * 256 + c];
        win[i][c] = v;
    }
    float w9[9];
#pragma unroll
    for (int j = 0; j < 9; ++j) w9[j] = dwc_w[c * 9 + j];
    float lw = ln_w[c], lb = ln_b[c], fd = fcd_w[c], fa = fca_w[c];
    __syncthreads();

    int lane = c & 63, wid = c >> 6;
#pragma unroll
    for (int p = 0; p < 8; ++p) {
        int pr = p & 1;
        float acc = 0.f;
#pragma unroll
        for (int j = 0; j < 9; ++j) {
            int r = j / 3, xc = p + (j - r * 3);
            acc += w9[j] * bf2f(win[r * 10 + xc][c]);
        }
        float s1 = acc, s2 = acc * acc;
#pragma unroll
        for (int off = 32; off >= 1; off >>= 1) {
            s1 += __shfl_down(s1, off);
            s2 += __shfl_down(s2, off);
        }
        if (lane == 0) { red[pr][0][wid] = s1; red[pr][1][wid] = s2; }
        __syncthreads();
        float tot1 = red[pr][0][0] + red[pr][0][1] + red[pr][0][2] + red[pr][0][3];
        float tot2 = red[pr][1][0] + red[pr][1][1] + red[pr][1][2] + red[pr][1][3];
        float mu  = tot1 * (1.f / 256.f);
        float var = tot2 * (1.f / 256.f) - mu * mu;
        float hn = (acc - mu) * rsqrtf(var + 1e-5f) * lw + lb;
        hn = fmaxf(hn, 0.f);
        float d1 = hn * fd, d2 = hn * fa;
#pragma unroll
        for (int off = 32; off >= 1; off >>= 1) {
            d1 += __shfl_down(d1, off);
            d2 += __shfl_down(d2, off);
        }
        if (lane == 0) { red[pr][2][wid] = d1; red[pr][3][wid] = d2; }
        __syncthreads();
        if (c == 0) {
            float r0 = red[pr][2][0] + red[pr][2][1] + red[pr][2][2] + red[pr][2][3];
            r0 = fmaxf(r0, 0.f);
            float t0 = red[pr][3][0] + red[pr][3][1] + red[pr][3][2] + red[pr][3][3];
            float theta = t0 / (1.f + fabsf(t0)) * 0.017453292519943295f;
            int pos = ((b << 6) + y) * 64 + xo + p;
            OX[pos] = r0 * cosf(theta);
            OY[pos] = r0 * sinf(theta);
        }
    }
}

// ---------------- K3: pack dconv_w (Co,C,3,3) f32 -> Bt (N=256 x K=2304) bf16 --------
__global__ void k_packB(const float* __restrict__ w, unsigned short* __restrict__ Bt)
{
    int idx = blockIdx.x * 256 + threadIdx.x;
    int o = idx / 2304, kk = idx - o * 2304;
    int k = kk >> 8, c = kk & 255;
    Bt[idx] = f2bf(w[(o * C_ + c) * 9 + k]);
}

// ---------------- K4: implicit GEMM deformable conv, dbuf + async-stage --------------
// 512 blocks (XCD-swizzled, 32 positions), 512 threads = 8 waves.
// Wave w: full M=32 (2 frags) x N-slice 32 (2 frags). No duplicated B reads.
__launch_bounds__(512, 4)
__global__ void k_main(const unsigned short* __restrict__ xT,
                       const float* __restrict__ OX, const float* __restrict__ OY,
                       const unsigned short* __restrict__ Bt,
                       const float* __restrict__ bias,
                       float* __restrict__ out)
{
    __shared__ __align__(16) unsigned char smem[32768];  // A dbuf 2x16KB / epilogue 32KB
    __shared__ float OXs[32], OYs[32];
    float* epi = (float*)smem;

    int tid = threadIdx.x;
    int bi = blockIdx.x;
    int swz = ((bi & 7) << 6) | (bi >> 3);
    int p0 = swz << 5;
    int b = p0 >> 12;
    int y = (p0 >> 6) & 63;
    int xh = p0 & 63;
    if (tid < 32) { OXs[tid] = OX[p0 + tid]; OYs[tid] = OY[p0 + tid]; }

    int lane = tid & 63, wid = tid >> 6;
    int l15 = lane & 15, l4 = lane >> 4;

    f32x4 acc[2][2];
#pragma unroll
    for (int m = 0; m < 2; ++m)
#pragma unroll
        for (int n = 0; n < 2; ++n) {
            acc[m][n].x = 0.f; acc[m][n].y = 0.f; acc[m][n].z = 0.f; acc[m][n].w = 0.f;
        }

    int gpos = tid >> 4;              // 0..31 position
    int cblk = (tid & 15) << 4;       // 16-channel chunk
    const unsigned short* xb = xT + (size_t)b * HW_ * C_;
    const unsigned short* brow = Bt + (size_t)(wid * 32 + l15) * 2304 + (l4 << 3);

    __syncthreads();
    float ox = OXs[gpos], oy = OYs[gpos];

    // gather address+weights for tap k (compile-time k after unroll)
#define GATHER(k, G, W00, W01, W10, W11)                                          \
    {                                                                             \
        int ky = (k) / 3, kx = (k) - ky * 3;                                      \
        float dyv = ((k) <= 4) ? ox : oy;                                         \
        float dxv = ((k) <= 3) ? ox : oy;                                         \
        float py = (float)(y - 1 + ky) + dyv;                                     \
        float px = (float)(xh + gpos - 1 + kx) + dxv;                             \
        float y0f = floorf(py), x0f = floorf(px);                                 \
        int y0 = (int)y0f, x0 = (int)x0f;                                         \
        int y1 = y0 + 1, x1 = x0 + 1;                                             \
        float wy1 = py - y0f, wy0 = 1.f - wy1;                                    \
        float wx1 = px - x0f, wx0 = 1.f - wx1;                                    \
        float vy0 = (y0 >= 0 && y0 < H_) ? 1.f : 0.f;                             \
        float vy1 = (y1 >= 0 && y1 < H_) ? 1.f : 0.f;                             \
        float vx0 = (x0 >= 0 && x0 < W_) ? 1.f : 0.f;                             \
        float vx1 = (x1 >= 0 && x1 < W_) ? 1.f : 0.f;                             \
        W00 = wy0 * wx0 * vy0 * vx0; W01 = wy0 * wx1 * vy0 * vx1;                 \
        W10 = wy1 * wx0 * vy1 * vx0; W11 = wy1 * wx1 * vy1 * vx1;                 \
        int y0c = min(max(y0, 0), H_ - 1), y1c = min(max(y1, 0), H_ - 1);         \
        int x0c = min(max(x0, 0), W_ - 1), x1c = min(max(x1, 0), W_ - 1);         \
        const unsigned short* q00 = xb + (size_t)((y0c << 6) + x0c) * 256 + cblk; \
        const unsigned short* q01 = xb + (size_t)((y0c << 6) + x1c) * 256 + cblk; \
        const unsigned short* q10 = xb + (size_t)((y1c << 6) + x0c) * 256 + cblk; \
        const unsigned short* q11 = xb + (size_t)((y1c << 6) + x1c) * 256 + cblk; \
        G[0] = *(const short8*)(q00); G[1] = *(const short8*)(q00 + 8);           \
        G[2] = *(const short8*)(q01); G[3] = *(const short8*)(q01 + 8);           \
        G[4] = *(const short8*)(q10); G[5] = *(const short8*)(q10 + 8);           \
        G[6] = *(const short8*)(q11); G[7] = *(const short8*)(q11 + 8);           \
    }

#define LERP_WRITE(buf, G, W00, W01, W10, W11)                                    \
    {                                                                             \
        unsigned rowbase = (unsigned)(buf)*16384u + (unsigned)gpos * 512u;        \
        unsigned swzr = ((unsigned)gpos & 7u) << 4;                               \
        _Pragma("unroll")                                                         \
        for (int hh = 0; hh < 2; ++hh) {                                          \
            short8 res;                                                           \
            _Pragma("unroll")                                                     \
            for (int j = 0; j < 8; ++j) {                                         \
                float a = bf2f((unsigned short)G[0 + hh][j]) * W00                \
                        + bf2f((unsigned short)G[2 + hh][j]) * W01                \
                        + bf2f((unsigned short)G[4 + hh][j]) * W10                \
                        + bf2f((unsigned short)G[6 + hh][j]) * W11;               \
                res[j] = (short)f2bf(a);                                          \
            }                                                                     \
            *(short8*)(smem + rowbase +                                           \
                       ((((unsigned)(cblk + hh * 8)) * 2u) ^ swzr)) = res;        \
        }                                                                         \
    }

    {
        short8 g0[8];
        float w00, w01, w10, w11;
        GATHER(0, g0, w00, w01, w10, w11);
        LERP_WRITE(0, g0, w00, w01, w10, w11);
    }
    __syncthreads();

#pragma unroll
    for (int k = 0; k < 9; ++k) {
        int t = k & 1;
        short8 g[8];
        float w00, w01, w10, w11;
        if (k < 8) {
            GATHER(k + 1, g, w00, w01, w10, w11);   // issue loads early (hide under MFMA)
        }
        // ---- MFMA phase on buf t, tap k ----
        {
            const unsigned short* bk = brow + (k << 8);
            unsigned abase = (unsigned)t * 16384u;
#pragma unroll
            for (int ks = 0; ks < 8; ++ks) {
                int c0b = ks * 64;           // byte offset of k-chunk
                short8 a[2];
#pragma unroll
                for (int m = 0; m < 2; ++m) {
                    int row = m * 16 + l15;
                    unsigned off = abase + (unsigned)row * 512u +
                                   (((unsigned)(c0b + (l4 << 4))) ^ (((unsigned)row & 7u) << 4));
                    a[m] = *(const short8*)(smem + off);
                }
                short8 bf0 = *(const short8*)(bk + ks * 32);
                short8 bf1 = *(const short8*)(bk + 16 * 2304 + ks * 32);
#pragma unroll
                for (int m = 0; m < 2; ++m) {
                    acc[m][0] = __builtin_amdgcn_mfma_f32_16x16x32_bf16(a[m], bf0, acc[m][0], 0, 0, 0);
                    acc[m][1] = __builtin_amdgcn_mfma_f32_16x16x32_bf16(a[m], bf1, acc[m][1], 0, 0, 0);
                }
            }
        }
        if (k < 8) {
            LERP_WRITE(t ^ 1, g, w00, w01, w10, w11);
        }
        __syncthreads();
    }

    // ---- epilogue ----
#pragma unroll
    for (int m = 0; m < 2; ++m)
#pragma unroll
        for (int n = 0; n < 2; ++n)
#pragma unroll
            for (int i = 0; i < 4; ++i) {
                int row = m * 16 + l4 * 4 + i;
                int col = wid * 32 + n * 16 + l15;
                epi[row * 256 + col] = acc[m][n][i];
            }
    __syncthreads();
    int o = tid >> 1;
    int wb = (tid & 1) << 4;
    float bv = bias[o];
    float* orow = out + (size_t)(((b * CO_ + o) * H_ + y) * W_) + xh + wb;
#pragma unroll
    for (int w4 = 0; w4 < 16; w4 += 4) {
        f32x4 v;
        v.x = epi[(wb + w4 + 0) * 256 + o] + bv;
        v.y = epi[(wb + w4 + 1) * 256 + o] + bv;
        v.z = epi[(wb + w4 + 2) * 256 + o] + bv;
        v.w = epi[(wb + w4 + 3) * 256 + o] + bv;
        *(f32x4*)(orow + w4) = v;
    }
}

extern "C" void kernel_launch(void* const* d_in, const int* in_sizes, int n_in,
                              void* d_out, int out_size, void* d_ws, size_t ws_size,
                              hipStream_t stream) {
    const float* x      = (const float*)d_in[0];
    const float* dwc_w  = (const float*)d_in[1];
    const float* ln_w   = (const float*)d_in[2];
    const float* ln_b   = (const float*)d_in[3];
    const float* fcd_w  = (const float*)d_in[4];
    const float* fca_w  = (const float*)d_in[5];
    const float* dconv_w= (const float*)d_in[6];
    const float* dconv_b= (const float*)d_in[7];
    float* out = (float*)d_out;

    unsigned char* ws = (unsigned char*)d_ws;
    unsigned short* xT = (unsigned short*)(ws);                 // 8 MB bf16 NHWC
    float* OX = (float*)(ws + 8388608);
    float* OY = (float*)(ws + 8454144);
    unsigned short* Bt = (unsigned short*)(ws + 8519680);

    k_transpose<<<1024, 256, 0, stream>>>(x, xT);
    k_packB<<<2304, 256, 0, stream>>>(dconv_w, Bt);
    k_offsets<<<2048, 256, 0, stream>>>(xT, dwc_w, ln_w, ln_b, fcd_w, fca_w, OX, OY);
    k_main<<<512, 512, 0, stream>>>(xT, OX, OY, Bt, dconv_b, out);
}